// Round 12
// baseline (311.408 us; speedup 1.0000x reference)
//
#include <hip/hip_runtime.h>
#include <stdint.h>

typedef float f32x4 __attribute__((ext_vector_type(4)));
typedef __bf16 bf16x8 __attribute__((ext_vector_type(8)));
typedef unsigned short u16;

__device__ __forceinline__ void gload_lds16(const void* g, void* l) {
  __builtin_amdgcn_global_load_lds(
      (__attribute__((address_space(1))) void*)(uintptr_t)(g),
      (__attribute__((address_space(3))) void*)(uint32_t)(uintptr_t)(l),
      16, 0, 0);
}

__device__ __forceinline__ u16 f2bf(float x) {
  __bf16 h = (__bf16)x;
  return *(u16*)&h;
}

__device__ __forceinline__ void barrier_raw() {
  __builtin_amdgcn_sched_barrier(0);
  __builtin_amdgcn_s_barrier();
  __builtin_amdgcn_sched_barrier(0);
}

#define VMCNT(n) asm volatile("s_waitcnt vmcnt(" #n ")" ::: "memory")

// ---------------- fused cast f32 -> bf16 for all 7 arrays ----------------
__global__ __launch_bounds__(256) void cast_all(
    const float* __restrict__ q, const float* __restrict__ k,
    const float* __restrict__ v, const float* __restrict__ wq,
    const float* __restrict__ wk, const float* __restrict__ wv,
    const float* __restrict__ wo, u16* __restrict__ out) {
  const int g = blockIdx.x;
  const float* in;
  int s;
  if (g < 8192) { in = q; s = 0; }
  else if (g < 14336) { in = k; s = 8192; }
  else if (g < 20480) { in = v; s = 14336; }
  else if (g < 21504) { in = wq; s = 20480; }
  else if (g < 22272) { in = wk; s = 21504; }
  else if (g < 23040) { in = wv; s = 22272; }
  else { in = wo; s = 23040; }
  const int li = (g - s) * 256 + threadIdx.x;
  float4 x = *((const float4*)in + li);
  unsigned lo = (unsigned)f2bf(x.x) | ((unsigned)f2bf(x.y) << 16);
  unsigned hi = (unsigned)f2bf(x.z) | ((unsigned)f2bf(x.w) << 16);
  ((uint2*)out)[(size_t)g * 256 + threadIdx.x] = make_uint2(lo, hi);
}

// ---------------- merged Q/K/V projection GEMM (fat waves) ----------------
// BM=256 x BN=128, block = 128 threads = 2 WAVES of 128x128 each:
// 16 ds_read_b128 feed 64 MFMA per wave per K-step (65.5K FLOP/read, 1.5x the
// 4-wave 128x64 layout). Rationale: R7/R10/R11 all measured pipes SUMMING
// (MFMA 31% + LDS 38% + VALU 17% ~= 86% of the K-step) regardless of barrier
// structure; raising the per-wave MFMA:LDS ratio attacks the split directly.
// 3-buffer LDS, single barrier, counted vmcnt (12 loads/thread in flight).
// acc[8][8] = 256 VGPR -> launch_bounds(128,1). Role grouping y>>3 keeps A
// panels XCD-L2-resident (R8: y%3 = -30%).
__global__ __launch_bounds__(128, 1) void proj_kernel(
    const u16* __restrict__ qb, const u16* __restrict__ kb,
    const u16* __restrict__ vb, const u16* __restrict__ wqb,
    const u16* __restrict__ wkb, const u16* __restrict__ wvb,
    const float* __restrict__ bq, const float* __restrict__ bk,
    const float* __restrict__ bv, u16* __restrict__ qpb,
    u16* __restrict__ kpb, u16* __restrict__ vtb) {
  __shared__ __align__(16) u16 As[3][256 * 32];
  __shared__ __align__(16) u16 Bs[3][128 * 32];
  const int tid = threadIdx.x;
  const int role = blockIdx.y >> 3;
  const int m0 = blockIdx.x * 256, n0 = (blockIdx.y & 7) * 128;
  const int K = (role == 0) ? 1024 : 768;
  const u16* A = (role == 0) ? qb : ((role == 1) ? kb : vb);
  const u16* Bt = (role == 0) ? wqb : ((role == 1) ? wkb : wvb);
  const float* bias = (role == 0) ? bq : ((role == 1) ? bk : bv);
  const int lane = tid & 63, w = tid >> 6;  // 2 waves
  const int l16 = lane & 15, lk = lane >> 4;
  const int nk = K >> 5;
  const int srow = tid >> 2;                       // 0..31
  const int sw = (tid & 3) ^ ((tid >> 3) & 3);     // pre-swizzled source chunk

  const u16* Ap = A + (size_t)(m0 + srow) * K + sw * 8;
  const u16* Bp = Bt + (size_t)(n0 + srow) * K + sw * 8;

  f32x4 acc[8][8] = {};

  auto stage = [&](int t, int ko) {
#pragma unroll
    for (int l = 0; l < 8; ++l)  // A: 256 rows, 32 rows/pass
      gload_lds16(Ap + (size_t)l * 32 * K + ko, As[t] + tid * 8 + l * 1024);
#pragma unroll
    for (int l = 0; l < 4; ++l)  // B: 128 rows
      gload_lds16(Bp + (size_t)l * 32 * K + ko, Bs[t] + tid * 8 + l * 1024);
  };

  // prologue: tiles 0,1 in flight (24 loads/thread)
  stage(0, 0);
  stage(1, 32);

  const int e2 = (l16 >> 1) & 3;  // read-side swizzle
  int cur = 0;
  for (int kt = 0; kt < nk; ++kt) {
    if (kt + 1 < nk) { VMCNT(12); } else { VMCNT(0); }
    barrier_raw();  // buf[cur] fully staged; buf[stg] fully consumed
    if (kt + 2 < nk) {
      const int stg = (cur >= 1) ? cur - 1 : 2;  // (cur+2)%3, consumed @ kt-1
      stage(stg, (kt + 2) << 5);
    }
    bf16x8 a[8], b[8];
#pragma unroll
    for (int i = 0; i < 8; ++i)
      a[i] = *(const bf16x8*)(As[cur] + (w * 128 + i * 16 + l16) * 32 + (lk ^ e2) * 8);
#pragma unroll
    for (int j = 0; j < 8; ++j)
      b[j] = *(const bf16x8*)(Bs[cur] + (j * 16 + l16) * 32 + (lk ^ e2) * 8);
    __builtin_amdgcn_s_setprio(1);
#pragma unroll
    for (int i = 0; i < 8; ++i)
#pragma unroll
      for (int j = 0; j < 8; ++j)
        acc[i][j] = __builtin_amdgcn_mfma_f32_16x16x32_bf16(a[i], b[j], acc[i][j], 0, 0, 0);
    __builtin_amdgcn_s_setprio(0);
    cur = (cur < 2) ? cur + 1 : 0;
  }

#pragma unroll
  for (int i = 0; i < 8; ++i) {
    const int mrow = m0 + w * 128 + i * 16 + lk * 4;
#pragma unroll
    for (int j = 0; j < 8; ++j) {
      const int col = n0 + j * 16 + l16;
      const float bval = bias[col];
      if (role == 0) {
#pragma unroll
        for (int r = 0; r < 4; ++r)
          qpb[(size_t)(mrow + r) * 1024 + col] = f2bf(acc[i][j][r] + bval);
      } else if (role == 1) {
#pragma unroll
        for (int r = 0; r < 4; ++r)
          kpb[(size_t)(mrow + r) * 1024 + col] = f2bf(acc[i][j][r] + bval);
      } else {  // vt[b][h][d][l], rows r are 4 consecutive l
        const int bb = mrow >> 10, l = mrow & 1023;
        const int hh = col >> 6, dd = col & 63;
        u16 u0 = f2bf(acc[i][j][0] + bval);
        u16 u1 = f2bf(acc[i][j][1] + bval);
        u16 u2 = f2bf(acc[i][j][2] + bval);
        u16 u3 = f2bf(acc[i][j][3] + bval);
        uint2 pkt = make_uint2((unsigned)u0 | ((unsigned)u1 << 16),
                               (unsigned)u2 | ((unsigned)u3 << 16));
        *(uint2*)(vtb + ((size_t)((bb * 16 + hh) * 64 + dd) << 10) + l) = pkt;
      }
    }
  }
}

// ---------------- fused masked flash attention ----------------
// grid = 2048 flat, block = 256 (4 waves x 16 q-rows). XCD-locality decode:
// bh = (bid&7) + 8*(bid>>7), qt = (bid>>3)&15 -> all 16 qt-blocks of a (b,h)
// share one XCD; its 256KB K/V panel stays L2-resident.
__global__ __launch_bounds__(256) void attn_kernel(
    const u16* __restrict__ qp, const u16* __restrict__ kp,
    const u16* __restrict__ vt, const int* __restrict__ mask,
    u16* __restrict__ out) {
  __shared__ __align__(16) u16 KV[2][2][64 * 64];  // [buf][0=K,1=V]
  __shared__ __align__(16) u16 Ps[4][16 * 64];     // XOR-swizzled (8-u16 chunks)
  const int tid = threadIdx.x;
  const int bid = blockIdx.x;
  const int qt = (bid >> 3) & 15;
  const int bh = (bid & 7) + ((bid >> 7) << 3);
  const int b = bh >> 4, h = bh & 15;
  const int lane = tid & 63, w = tid >> 6;
  const int l16 = lane & 15, lk = lane >> 4;
  const int srow = tid >> 3, schunk = tid & 7;
  const int sw = schunk ^ (srow & 7);  // pre-swizzled source chunk

  // per-wave prefix-mask popcount -> len (no LDS, no cross-wave comm)
  int cnt = 0;
  {
    const int4* mp = (const int4*)(mask + (b << 10));
#pragma unroll
    for (int i = 0; i < 4; ++i) {
      const int4 mv = mp[lane * 4 + i];
      cnt += (mv.x ? 1 : 0) + (mv.y ? 1 : 0) + (mv.z ? 1 : 0) + (mv.w ? 1 : 0);
    }
#pragma unroll
    for (int off = 1; off < 64; off <<= 1) cnt += __shfl_xor(cnt, off);
  }
  const int ntile = (cnt + 63) >> 6;
  const int rem = cnt & 63;

  // stage Q into KV[1][0] (temporary), K0/V0 into KV[0]
#pragma unroll
  for (int p = 0; p < 2; ++p) {
    gload_lds16(qp + (((size_t)(b * 1024 + qt * 64 + p * 32 + srow)) << 10) + h * 64 + sw * 8,
                KV[1][0] + tid * 8 + p * 2048);
    gload_lds16(kp + (((size_t)(b * 1024 + p * 32 + srow)) << 10) + h * 64 + sw * 8,
                KV[0][0] + tid * 8 + p * 2048);
    gload_lds16(vt + (((size_t)((b * 16 + h) * 64 + p * 32 + srow)) << 10) + sw * 8,
                KV[0][1] + tid * 8 + p * 2048);
  }
  __syncthreads();
  const int qrow = w * 16 + l16, qs = qrow & 7;
  bf16x8 aq0 = *(const bf16x8*)(KV[1][0] + qrow * 64 + (lk ^ qs) * 8);
  bf16x8 aq1 = *(const bf16x8*)(KV[1][0] + qrow * 64 + ((lk + 4) ^ qs) * 8);
  __syncthreads();  // all waves done with Q region before buf1 prefetch

  const float SC2 = 0.18033688011112042f;  // 0.125 * log2(e)
  float lsumq = 0.f;                       // row-sum for q = l16 (per lane)
  f32x4 oacc[4] = {};
  const int e7 = l16 & 7;

  int cur = 0;
  for (int kt = 0; kt < ntile; ++kt) {
    // issue next-tile prefetch FIRST (stays in flight across compute)
    if (kt + 1 < ntile) {
#pragma unroll
      for (int p = 0; p < 2; ++p) {
        gload_lds16(kp + (((size_t)(b * 1024 + (kt + 1) * 64 + p * 32 + srow)) << 10) + h * 64 + sw * 8,
                    KV[cur ^ 1][0] + tid * 8 + p * 2048);
        gload_lds16(vt + (((size_t)((b * 16 + h) * 64 + p * 32 + srow)) << 10) + (kt + 1) * 64 + sw * 8,
                    KV[cur ^ 1][1] + tid * 8 + p * 2048);
      }
    }
    const u16* Kb = KV[cur][0];
    const u16* Vb = KV[cur][1];

    // QK^T, swapped operands: lane holds S[key=nf*16+lk*4+r][q=l16]
    f32x4 sfr[4] = {};
    __builtin_amdgcn_s_setprio(1);
#pragma unroll
    for (int nf = 0; nf < 4; ++nf) {
      const int krow = nf * 16 + l16;
      bf16x8 bk0 = *(const bf16x8*)(Kb + krow * 64 + (lk ^ e7) * 8);
      bf16x8 bk1 = *(const bf16x8*)(Kb + krow * 64 + ((lk + 4) ^ e7) * 8);
      sfr[nf] = __builtin_amdgcn_mfma_f32_16x16x32_bf16(bk0, aq0, sfr[nf], 0, 0, 0);
      sfr[nf] = __builtin_amdgcn_mfma_f32_16x16x32_bf16(bk1, aq1, sfr[nf], 0, 0, 0);
    }
    __builtin_amdgcn_s_setprio(0);

    // fixed-shift softmax; only the single partial tile needs mask math
    const bool partial = (kt == ntile - 1) && (rem != 0);
    u16* Pw = &Ps[w][0];
#pragma unroll
    for (int nf = 0; nf < 4; ++nf) {
      float pv0 = __builtin_amdgcn_exp2f(sfr[nf][0] * SC2);
      float pv1 = __builtin_amdgcn_exp2f(sfr[nf][1] * SC2);
      float pv2 = __builtin_amdgcn_exp2f(sfr[nf][2] * SC2);
      float pv3 = __builtin_amdgcn_exp2f(sfr[nf][3] * SC2);
      if (partial) {
        const int k0 = nf * 16 + lk * 4;
        pv0 = (k0 + 0 < rem) ? pv0 : 0.f;
        pv1 = (k0 + 1 < rem) ? pv1 : 0.f;
        pv2 = (k0 + 2 < rem) ? pv2 : 0.f;
        pv3 = (k0 + 3 < rem) ? pv3 : 0.f;
      }
      lsumq += (pv0 + pv1) + (pv2 + pv3);
      unsigned lo = (unsigned)f2bf(pv0) | ((unsigned)f2bf(pv1) << 16);
      unsigned hi = (unsigned)f2bf(pv2) | ((unsigned)f2bf(pv3) << 16);
      // chunk (nf*2 + lk>>1) XOR (l16&7), sub-slot lk&1
      *(uint2*)(Pw + l16 * 64 + (((nf * 2 + (lk >> 1)) ^ e7) * 8 + (lk & 1) * 4)) =
          make_uint2(lo, hi);
    }

    bf16x8 ap0 = *(const bf16x8*)(Pw + l16 * 64 + ((lk ^ e7) * 8));
    bf16x8 ap1 = *(const bf16x8*)(Pw + l16 * 64 + (((4 + lk) ^ e7) * 8));
    __builtin_amdgcn_s_setprio(1);
#pragma unroll
    for (int nf = 0; nf < 4; ++nf) {
      const int vrow = nf * 16 + l16;
      bf16x8 bv0 = *(const bf16x8*)(Vb + vrow * 64 + (lk ^ e7) * 8);
      bf16x8 bv1 = *(const bf16x8*)(Vb + vrow * 64 + ((lk + 4) ^ e7) * 8);
      oacc[nf] = __builtin_amdgcn_mfma_f32_16x16x32_bf16(ap0, bv0, oacc[nf], 0, 0, 0);
      oacc[nf] = __builtin_amdgcn_mfma_f32_16x16x32_bf16(ap1, bv1, oacc[nf], 0, 0, 0);
    }
    __builtin_amdgcn_s_setprio(0);

    __syncthreads();  // drains prefetch (vmcnt0) + all waves done with KV[cur]
    cur ^= 1;
  }

  // reduce row-sum across the 4 lanes sharing l16, redistribute to out layout
  lsumq += __shfl_xor(lsumq, 16);
  lsumq += __shfl_xor(lsumq, 32);
  float rinv[4];
#pragma unroll
  for (int r = 0; r < 4; ++r) rinv[r] = 1.0f / __shfl(lsumq, lk * 4 + r);

#pragma unroll
  for (int nf = 0; nf < 4; ++nf)
#pragma unroll
    for (int r = 0; r < 4; ++r) {
      const int tok = b * 1024 + qt * 64 + w * 16 + lk * 4 + r;
      const int col = h * 64 + nf * 16 + l16;
      out[((size_t)tok << 10) + col] = f2bf(oacc[nf][r] * rinv[r]);
    }
}

// ---------------- O-projection GEMM + bias + f32 residual ----------------
// Same fat-wave structure as proj: BM=256 x BN=128, 2 waves of 128x128,
// 3-buffer single-barrier, vmcnt(12). grid (32, 8).
__global__ __launch_bounds__(128, 1) void gemm_o(
    const u16* __restrict__ A, const u16* __restrict__ Bt,
    const float* __restrict__ bias, float* __restrict__ Cf,
    const float* __restrict__ res) {
  __shared__ __align__(16) u16 As[3][256 * 32];
  __shared__ __align__(16) u16 Bs[3][128 * 32];
  const int K = 1024, N = 1024, nk = 32;
  const int tid = threadIdx.x;
  const int m0 = blockIdx.x * 256, n0 = blockIdx.y * 128;
  const int lane = tid & 63, w = tid >> 6;
  const int l16 = lane & 15, lk = lane >> 4;
  const int srow = tid >> 2;
  const int sw = (tid & 3) ^ ((tid >> 3) & 3);
  const int e2 = (l16 >> 1) & 3;

  const u16* Ap = A + (size_t)(m0 + srow) * K + sw * 8;
  const u16* Bp = Bt + (size_t)(n0 + srow) * K + sw * 8;

  f32x4 acc[8][8] = {};

  auto stage = [&](int t, int ko) {
#pragma unroll
    for (int l = 0; l < 8; ++l)
      gload_lds16(Ap + (size_t)l * 32 * K + ko, As[t] + tid * 8 + l * 1024);
#pragma unroll
    for (int l = 0; l < 4; ++l)
      gload_lds16(Bp + (size_t)l * 32 * K + ko, Bs[t] + tid * 8 + l * 1024);
  };

  stage(0, 0);
  stage(1, 32);

  int cur = 0;
  for (int kt = 0; kt < nk; ++kt) {
    if (kt + 1 < nk) { VMCNT(12); } else { VMCNT(0); }
    barrier_raw();
    if (kt + 2 < nk) {
      const int stg = (cur >= 1) ? cur - 1 : 2;
      stage(stg, (kt + 2) << 5);
    }
    bf16x8 a[8], b[8];
#pragma unroll
    for (int i = 0; i < 8; ++i)
      a[i] = *(const bf16x8*)(As[cur] + (w * 128 + i * 16 + l16) * 32 + (lk ^ e2) * 8);
#pragma unroll
    for (int j = 0; j < 8; ++j)
      b[j] = *(const bf16x8*)(Bs[cur] + (j * 16 + l16) * 32 + (lk ^ e2) * 8);
    __builtin_amdgcn_s_setprio(1);
#pragma unroll
    for (int i = 0; i < 8; ++i)
#pragma unroll
      for (int j = 0; j < 8; ++j)
        acc[i][j] = __builtin_amdgcn_mfma_f32_16x16x32_bf16(a[i], b[j], acc[i][j], 0, 0, 0);
    __builtin_amdgcn_s_setprio(0);
    cur = (cur < 2) ? cur + 1 : 0;
  }

#pragma unroll
  for (int i = 0; i < 8; ++i) {
    const int mrow = m0 + w * 128 + i * 16 + lk * 4;
#pragma unroll
    for (int j = 0; j < 8; ++j) {
      const int col = n0 + j * 16 + l16;
      const float bval = bias[col];
#pragma unroll
      for (int r = 0; r < 4; ++r) {
        const size_t idx = (size_t)(mrow + r) * N + col;
        Cf[idx] = acc[i][j][r] + bval + res[idx];
      }
    }
  }
}

// ---------------- in-place LayerNorm over rows of 1024 f32 ----------------
__global__ __launch_bounds__(256) void ln_kernel(float* __restrict__ y,
                                                 const float* __restrict__ gamma,
                                                 const float* __restrict__ beta) {
  __shared__ float ssum[4], ssq[4];
  const int tid = threadIdx.x;
  float* yr = y + ((size_t)blockIdx.x << 10);
  float4 v = *((const float4*)yr + tid);
  float s = v.x + v.y + v.z + v.w;
  float q2 = v.x * v.x + v.y * v.y + v.z * v.z + v.w * v.w;
#pragma unroll
  for (int off = 1; off < 64; off <<= 1) {
    s += __shfl_xor(s, off);
    q2 += __shfl_xor(q2, off);
  }
  if ((tid & 63) == 0) { ssum[tid >> 6] = s; ssq[tid >> 6] = q2; }
  __syncthreads();
  s = ssum[0] + ssum[1] + ssum[2] + ssum[3];
  q2 = ssq[0] + ssq[1] + ssq[2] + ssq[3];
  const float mu = s * (1.0f / 1024.0f);
  const float rstd = rsqrtf(q2 * (1.0f / 1024.0f) - mu * mu + 1e-5f);
  float4 g = *((const float4*)gamma + tid);
  float4 be = *((const float4*)beta + tid);
  float4 o;
  o.x = (v.x - mu) * rstd * g.x + be.x;
  o.y = (v.y - mu) * rstd * g.y + be.y;
  o.z = (v.z - mu) * rstd * g.z + be.z;
  o.w = (v.w - mu) * rstd * g.w + be.w;
  *((float4*)yr + tid) = o;
}

extern "C" void kernel_launch(void* const* d_in, const int* in_sizes, int n_in,
                              void* d_out, int out_size, void* d_ws, size_t ws_size,
                              hipStream_t stream) {
  (void)in_sizes; (void)n_in; (void)out_size; (void)ws_size;
  const float* q = (const float*)d_in[0];
  const float* k = (const float*)d_in[1];
  const float* v = (const float*)d_in[2];
  const int* msk = (const int*)d_in[3];
  const float* Wq = (const float*)d_in[4];
  const float* bq = (const float*)d_in[5];
  const float* Wk = (const float*)d_in[6];
  const float* bk = (const float*)d_in[7];
  const float* Wv = (const float*)d_in[8];
  const float* bv = (const float*)d_in[9];
  const float* Wo = (const float*)d_in[10];
  const float* bo = (const float*)d_in[11];
  const float* gamma = (const float*)d_in[12];
  const float* beta = (const float*)d_in[13];
  float* out = (float*)d_out;

  char* p = (char*)d_ws;
  auto take = [&p](size_t bytes) {
    char* r = p;
    p += (bytes + 255) & ~(size_t)255;
    return r;
  };
  u16* qb = (u16*)take(8192ull * 1024 * 2);
  u16* kb = (u16*)take(8192ull * 768 * 2);
  u16* vb = (u16*)take(8192ull * 768 * 2);
  u16* wqb = (u16*)take(1024ull * 1024 * 2);
  u16* wkb = (u16*)take(1024ull * 768 * 2);
  u16* wvb = (u16*)take(1024ull * 768 * 2);
  u16* wob = (u16*)take(1024ull * 1024 * 2);
  u16* qpb = (u16*)take(8192ull * 1024 * 2);
  u16* kpb = (u16*)take(8192ull * 1024 * 2);
  u16* vtb = (u16*)take(8192ull * 1024 * 2);  // [B][H][64][1024]
  u16* atb = (u16*)take(8192ull * 1024 * 2);

  cast_all<<<dim3(24064), 256, 0, stream>>>(q, k, v, Wq, Wk, Wv, Wo, qb);

  proj_kernel<<<dim3(32, 24), 128, 0, stream>>>(qb, kb, vb, wqb, wkb, wvb,
                                                bq, bk, bv, qpb, kpb, vtb);

  attn_kernel<<<dim3(2048), 256, 0, stream>>>(qpb, kpb, vtb, msk, atb);

  gemm_o<<<dim3(32, 8), 128, 0, stream>>>(atb, wob, bo, out, q);

  ln_kernel<<<dim3(8192), 256, 0, stream>>>(out, gamma, beta);
}

// Round 13
// 173.562 us; speedup vs baseline: 1.7942x; 1.7942x over previous
//
#include <hip/hip_runtime.h>
#include <stdint.h>

typedef float f32x4 __attribute__((ext_vector_type(4)));
typedef __bf16 bf16x8 __attribute__((ext_vector_type(8)));
typedef unsigned short u16;

__device__ __forceinline__ void gload_lds16(const void* g, void* l) {
  __builtin_amdgcn_global_load_lds(
      (__attribute__((address_space(1))) void*)(uintptr_t)(g),
      (__attribute__((address_space(3))) void*)(uint32_t)(uintptr_t)(l),
      16, 0, 0);
}

__device__ __forceinline__ u16 f2bf(float x) {
  __bf16 h = (__bf16)x;
  return *(u16*)&h;
}

__device__ __forceinline__ void barrier_raw() {
  __builtin_amdgcn_sched_barrier(0);
  __builtin_amdgcn_s_barrier();
  __builtin_amdgcn_sched_barrier(0);
}

#define VMCNT(n) asm volatile("s_waitcnt vmcnt(" #n ")" ::: "memory")

// ---------------- fused cast f32 -> bf16 for all 7 arrays ----------------
__global__ __launch_bounds__(256) void cast_all(
    const float* __restrict__ q, const float* __restrict__ k,
    const float* __restrict__ v, const float* __restrict__ wq,
    const float* __restrict__ wk, const float* __restrict__ wv,
    const float* __restrict__ wo, u16* __restrict__ out) {
  const int g = blockIdx.x;
  const float* in;
  int s;
  if (g < 8192) { in = q; s = 0; }
  else if (g < 14336) { in = k; s = 8192; }
  else if (g < 20480) { in = v; s = 14336; }
  else if (g < 21504) { in = wq; s = 20480; }
  else if (g < 22272) { in = wk; s = 21504; }
  else if (g < 23040) { in = wv; s = 22272; }
  else { in = wo; s = 23040; }
  const int li = (g - s) * 256 + threadIdx.x;
  float4 x = *((const float4*)in + li);
  unsigned lo = (unsigned)f2bf(x.x) | ((unsigned)f2bf(x.y) << 16);
  unsigned hi = (unsigned)f2bf(x.z) | ((unsigned)f2bf(x.w) << 16);
  ((uint2*)out)[(size_t)g * 256 + threadIdx.x] = make_uint2(lo, hi);
}

// ---------------- merged Q/K/V projection GEMM ----------------
// BM=256 x BN=128, 4 waves (128x64/wave). SINGLE-barrier K-loop, 3 buffers:
//   [vmcnt(6) -> barrier -> stage(kt+2) -> reads(kt) -> MFMA(kt)]
// This is the measured floor of the 2-barrier-class structure (66us, ~650 TF
// effective at K=1024/768): reg-dbuf frags (R9: 88us), two-barrier (R10: 66),
// fat 128x128 waves at 1 wave/SIMD (R12: 192us, MfmaUtil 8.8%) all lose or
// tie. 2 waves/SIMD minimum is required for any latency hiding (R12 lesson).
// Role grouping y>>3 keeps A panels XCD-L2-resident (R8: y%3 = -30%).
__global__ __launch_bounds__(256, 2) void proj_kernel(
    const u16* __restrict__ qb, const u16* __restrict__ kb,
    const u16* __restrict__ vb, const u16* __restrict__ wqb,
    const u16* __restrict__ wkb, const u16* __restrict__ wvb,
    const float* __restrict__ bq, const float* __restrict__ bk,
    const float* __restrict__ bv, u16* __restrict__ qpb,
    u16* __restrict__ kpb, u16* __restrict__ vtb) {
  __shared__ __align__(16) u16 As[3][256 * 32];
  __shared__ __align__(16) u16 Bs[3][128 * 32];
  const int tid = threadIdx.x;
  const int role = blockIdx.y >> 3;
  const int m0 = blockIdx.x * 256, n0 = (blockIdx.y & 7) * 128;
  const int K = (role == 0) ? 1024 : 768;
  const u16* A = (role == 0) ? qb : ((role == 1) ? kb : vb);
  const u16* Bt = (role == 0) ? wqb : ((role == 1) ? wkb : wvb);
  const float* bias = (role == 0) ? bq : ((role == 1) ? bk : bv);
  const int lane = tid & 63, w = tid >> 6;
  const int wr = w >> 1, wc = w & 1;
  const int l16 = lane & 15, lk = lane >> 4;
  const int nk = K >> 5;
  const int srow = tid >> 2;
  const int sw = (tid & 3) ^ ((tid >> 3) & 3);

  const u16* Ap = A + (size_t)(m0 + srow) * K + sw * 8;
  const u16* Bp = Bt + (size_t)(n0 + srow) * K + sw * 8;

  f32x4 acc[8][4] = {};

  auto stage = [&](int t, int ko) {
#pragma unroll
    for (int l = 0; l < 4; ++l)
      gload_lds16(Ap + (size_t)l * 64 * K + ko, As[t] + tid * 8 + l * 2048);
#pragma unroll
    for (int l = 0; l < 2; ++l)
      gload_lds16(Bp + (size_t)l * 64 * K + ko, Bs[t] + tid * 8 + l * 2048);
  };

  // prologue: tiles 0,1 in flight (12 loads)
  stage(0, 0);
  stage(1, 32);

  const int e2 = (l16 >> 1) & 3;  // read-side swizzle
  int cur = 0;
  for (int kt = 0; kt < nk; ++kt) {
    if (kt + 1 < nk) { VMCNT(6); } else { VMCNT(0); }
    barrier_raw();  // buf[cur] fully staged; buf[stg] fully consumed
    if (kt + 2 < nk) {
      const int stg = (cur >= 1) ? cur - 1 : 2;  // (cur+2)%3, consumed @ kt-1
      stage(stg, (kt + 2) << 5);
    }
    bf16x8 a[8], b[4];
#pragma unroll
    for (int i = 0; i < 8; ++i)
      a[i] = *(const bf16x8*)(As[cur] + (wr * 128 + i * 16 + l16) * 32 + (lk ^ e2) * 8);
#pragma unroll
    for (int j = 0; j < 4; ++j)
      b[j] = *(const bf16x8*)(Bs[cur] + (wc * 64 + j * 16 + l16) * 32 + (lk ^ e2) * 8);
    __builtin_amdgcn_s_setprio(1);
#pragma unroll
    for (int i = 0; i < 8; ++i)
#pragma unroll
      for (int j = 0; j < 4; ++j)
        acc[i][j] = __builtin_amdgcn_mfma_f32_16x16x32_bf16(a[i], b[j], acc[i][j], 0, 0, 0);
    __builtin_amdgcn_s_setprio(0);
    cur = (cur < 2) ? cur + 1 : 0;
  }

#pragma unroll
  for (int i = 0; i < 8; ++i) {
    const int mrow = m0 + wr * 128 + i * 16 + lk * 4;
#pragma unroll
    for (int j = 0; j < 4; ++j) {
      const int col = n0 + wc * 64 + j * 16 + l16;
      const float bval = bias[col];
      if (role == 0) {
#pragma unroll
        for (int r = 0; r < 4; ++r)
          qpb[(size_t)(mrow + r) * 1024 + col] = f2bf(acc[i][j][r] + bval);
      } else if (role == 1) {
#pragma unroll
        for (int r = 0; r < 4; ++r)
          kpb[(size_t)(mrow + r) * 1024 + col] = f2bf(acc[i][j][r] + bval);
      } else {  // vt[b][h][d][l], rows r are 4 consecutive l
        const int bb = mrow >> 10, l = mrow & 1023;
        const int hh = col >> 6, dd = col & 63;
        u16 u0 = f2bf(acc[i][j][0] + bval);
        u16 u1 = f2bf(acc[i][j][1] + bval);
        u16 u2 = f2bf(acc[i][j][2] + bval);
        u16 u3 = f2bf(acc[i][j][3] + bval);
        uint2 pkt = make_uint2((unsigned)u0 | ((unsigned)u1 << 16),
                               (unsigned)u2 | ((unsigned)u3 << 16));
        *(uint2*)(vtb + ((size_t)((bb * 16 + hh) * 64 + dd) << 10) + l) = pkt;
      }
    }
  }
}

// ---------------- fused masked flash attention ----------------
// grid = 2048 flat, block = 256 (4 waves x 16 q-rows). XCD-locality decode:
// bh = (bid&7) + 8*(bid>>7), qt = (bid>>3)&15 -> all 16 qt-blocks of a (b,h)
// share one XCD; its 256KB K/V panel stays L2-resident.
__global__ __launch_bounds__(256) void attn_kernel(
    const u16* __restrict__ qp, const u16* __restrict__ kp,
    const u16* __restrict__ vt, const int* __restrict__ mask,
    u16* __restrict__ out) {
  __shared__ __align__(16) u16 KV[2][2][64 * 64];  // [buf][0=K,1=V]
  __shared__ __align__(16) u16 Ps[4][16 * 64];     // XOR-swizzled (8-u16 chunks)
  const int tid = threadIdx.x;
  const int bid = blockIdx.x;
  const int qt = (bid >> 3) & 15;
  const int bh = (bid & 7) + ((bid >> 7) << 3);
  const int b = bh >> 4, h = bh & 15;
  const int lane = tid & 63, w = tid >> 6;
  const int l16 = lane & 15, lk = lane >> 4;
  const int srow = tid >> 3, schunk = tid & 7;
  const int sw = schunk ^ (srow & 7);  // pre-swizzled source chunk

  // per-wave prefix-mask popcount -> len (no LDS, no cross-wave comm)
  int cnt = 0;
  {
    const int4* mp = (const int4*)(mask + (b << 10));
#pragma unroll
    for (int i = 0; i < 4; ++i) {
      const int4 mv = mp[lane * 4 + i];
      cnt += (mv.x ? 1 : 0) + (mv.y ? 1 : 0) + (mv.z ? 1 : 0) + (mv.w ? 1 : 0);
    }
#pragma unroll
    for (int off = 1; off < 64; off <<= 1) cnt += __shfl_xor(cnt, off);
  }
  const int ntile = (cnt + 63) >> 6;
  const int rem = cnt & 63;

  // stage Q into KV[1][0] (temporary), K0/V0 into KV[0]
#pragma unroll
  for (int p = 0; p < 2; ++p) {
    gload_lds16(qp + (((size_t)(b * 1024 + qt * 64 + p * 32 + srow)) << 10) + h * 64 + sw * 8,
                KV[1][0] + tid * 8 + p * 2048);
    gload_lds16(kp + (((size_t)(b * 1024 + p * 32 + srow)) << 10) + h * 64 + sw * 8,
                KV[0][0] + tid * 8 + p * 2048);
    gload_lds16(vt + (((size_t)((b * 16 + h) * 64 + p * 32 + srow)) << 10) + sw * 8,
                KV[0][1] + tid * 8 + p * 2048);
  }
  __syncthreads();
  const int qrow = w * 16 + l16, qs = qrow & 7;
  bf16x8 aq0 = *(const bf16x8*)(KV[1][0] + qrow * 64 + (lk ^ qs) * 8);
  bf16x8 aq1 = *(const bf16x8*)(KV[1][0] + qrow * 64 + ((lk + 4) ^ qs) * 8);
  __syncthreads();  // all waves done with Q region before buf1 prefetch

  const float SC2 = 0.18033688011112042f;  // 0.125 * log2(e)
  float lsumq = 0.f;                       // row-sum for q = l16 (per lane)
  f32x4 oacc[4] = {};
  const int e7 = l16 & 7;

  int cur = 0;
  for (int kt = 0; kt < ntile; ++kt) {
    // issue next-tile prefetch FIRST (stays in flight across compute)
    if (kt + 1 < ntile) {
#pragma unroll
      for (int p = 0; p < 2; ++p) {
        gload_lds16(kp + (((size_t)(b * 1024 + (kt + 1) * 64 + p * 32 + srow)) << 10) + h * 64 + sw * 8,
                    KV[cur ^ 1][0] + tid * 8 + p * 2048);
        gload_lds16(vt + (((size_t)((b * 16 + h) * 64 + p * 32 + srow)) << 10) + (kt + 1) * 64 + sw * 8,
                    KV[cur ^ 1][1] + tid * 8 + p * 2048);
      }
    }
    const u16* Kb = KV[cur][0];
    const u16* Vb = KV[cur][1];

    // QK^T, swapped operands: lane holds S[key=nf*16+lk*4+r][q=l16]
    f32x4 sfr[4] = {};
    __builtin_amdgcn_s_setprio(1);
#pragma unroll
    for (int nf = 0; nf < 4; ++nf) {
      const int krow = nf * 16 + l16;
      bf16x8 bk0 = *(const bf16x8*)(Kb + krow * 64 + (lk ^ e7) * 8);
      bf16x8 bk1 = *(const bf16x8*)(Kb + krow * 64 + ((lk + 4) ^ e7) * 8);
      sfr[nf] = __builtin_amdgcn_mfma_f32_16x16x32_bf16(bk0, aq0, sfr[nf], 0, 0, 0);
      sfr[nf] = __builtin_amdgcn_mfma_f32_16x16x32_bf16(bk1, aq1, sfr[nf], 0, 0, 0);
    }
    __builtin_amdgcn_s_setprio(0);

    // fixed-shift softmax; only the single partial tile needs mask math
    const bool partial = (kt == ntile - 1) && (rem != 0);
    u16* Pw = &Ps[w][0];
#pragma unroll
    for (int nf = 0; nf < 4; ++nf) {
      float pv0 = __builtin_amdgcn_exp2f(sfr[nf][0] * SC2);
      float pv1 = __builtin_amdgcn_exp2f(sfr[nf][1] * SC2);
      float pv2 = __builtin_amdgcn_exp2f(sfr[nf][2] * SC2);
      float pv3 = __builtin_amdgcn_exp2f(sfr[nf][3] * SC2);
      if (partial) {
        const int k0 = nf * 16 + lk * 4;
        pv0 = (k0 + 0 < rem) ? pv0 : 0.f;
        pv1 = (k0 + 1 < rem) ? pv1 : 0.f;
        pv2 = (k0 + 2 < rem) ? pv2 : 0.f;
        pv3 = (k0 + 3 < rem) ? pv3 : 0.f;
      }
      lsumq += (pv0 + pv1) + (pv2 + pv3);
      unsigned lo = (unsigned)f2bf(pv0) | ((unsigned)f2bf(pv1) << 16);
      unsigned hi = (unsigned)f2bf(pv2) | ((unsigned)f2bf(pv3) << 16);
      // chunk (nf*2 + lk>>1) XOR (l16&7), sub-slot lk&1
      *(uint2*)(Pw + l16 * 64 + (((nf * 2 + (lk >> 1)) ^ e7) * 8 + (lk & 1) * 4)) =
          make_uint2(lo, hi);
    }

    bf16x8 ap0 = *(const bf16x8*)(Pw + l16 * 64 + ((lk ^ e7) * 8));
    bf16x8 ap1 = *(const bf16x8*)(Pw + l16 * 64 + (((4 + lk) ^ e7) * 8));
    __builtin_amdgcn_s_setprio(1);
#pragma unroll
    for (int nf = 0; nf < 4; ++nf) {
      const int vrow = nf * 16 + l16;
      bf16x8 bv0 = *(const bf16x8*)(Vb + vrow * 64 + (lk ^ e7) * 8);
      bf16x8 bv1 = *(const bf16x8*)(Vb + vrow * 64 + ((lk + 4) ^ e7) * 8);
      oacc[nf] = __builtin_amdgcn_mfma_f32_16x16x32_bf16(ap0, bv0, oacc[nf], 0, 0, 0);
      oacc[nf] = __builtin_amdgcn_mfma_f32_16x16x32_bf16(ap1, bv1, oacc[nf], 0, 0, 0);
    }
    __builtin_amdgcn_s_setprio(0);

    __syncthreads();  // drains prefetch (vmcnt0) + all waves done with KV[cur]
    cur ^= 1;
  }

  // reduce row-sum across the 4 lanes sharing l16, redistribute to out layout
  lsumq += __shfl_xor(lsumq, 16);
  lsumq += __shfl_xor(lsumq, 32);
  float rinv[4];
#pragma unroll
  for (int r = 0; r < 4; ++r) rinv[r] = 1.0f / __shfl(lsumq, lk * 4 + r);

#pragma unroll
  for (int nf = 0; nf < 4; ++nf)
#pragma unroll
    for (int r = 0; r < 4; ++r) {
      const int tok = b * 1024 + qt * 64 + w * 16 + lk * 4 + r;
      const int col = h * 64 + nf * 16 + l16;
      out[((size_t)tok << 10) + col] = f2bf(oacc[nf][r] * rinv[r]);
    }
}

// ---------------- O-projection GEMM + bias + f32 residual ----------------
// Same single-barrier 3-buffer K-loop as proj (vmcnt slack = 4);
// 48KB LDS -> 3 blocks/CU.
__global__ __launch_bounds__(256, 3) void gemm_o(
    const u16* __restrict__ A, const u16* __restrict__ Bt,
    const float* __restrict__ bias, float* __restrict__ Cf,
    const float* __restrict__ res) {
  __shared__ __align__(16) u16 As[3][128 * 32];
  __shared__ __align__(16) u16 Bs[3][128 * 32];
  const int K = 1024, N = 1024, nk = 32;
  const int tid = threadIdx.x;
  const int m0 = blockIdx.x * 128, n0 = blockIdx.y * 128;
  const int lane = tid & 63, w = tid >> 6;
  const int wr = w >> 1, wc = w & 1;
  const int l16 = lane & 15, lk = lane >> 4;
  const int srow = tid >> 2;
  const int sw = (tid & 3) ^ ((tid >> 3) & 3);
  const int e2 = (l16 >> 1) & 3;

  const u16* Ap = A + (size_t)(m0 + srow) * K + sw * 8;
  const u16* Bp = Bt + (size_t)(n0 + srow) * K + sw * 8;

  f32x4 acc[4][4] = {};

  auto stage = [&](int t, int ko) {
#pragma unroll
    for (int p = 0; p < 2; ++p) {
      gload_lds16(Ap + (size_t)p * 64 * K + ko, As[t] + tid * 8 + p * 2048);
      gload_lds16(Bp + (size_t)p * 64 * K + ko, Bs[t] + tid * 8 + p * 2048);
    }
  };

  stage(0, 0);
  stage(1, 32);

  int cur = 0;
  for (int kt = 0; kt < nk; ++kt) {
    if (kt + 1 < nk) { VMCNT(4); } else { VMCNT(0); }
    barrier_raw();
    if (kt + 2 < nk) {
      const int stg = (cur >= 1) ? cur - 1 : 2;
      stage(stg, (kt + 2) << 5);
    }
    bf16x8 a[4], b[4];
#pragma unroll
    for (int i = 0; i < 4; ++i)
      a[i] = *(const bf16x8*)(As[cur] + (wr * 64 + i * 16 + l16) * 32 + (lk ^ e2) * 8);
#pragma unroll
    for (int j = 0; j < 4; ++j)
      b[j] = *(const bf16x8*)(Bs[cur] + (wc * 64 + j * 16 + l16) * 32 + (lk ^ e2) * 8);
    __builtin_amdgcn_s_setprio(1);
#pragma unroll
    for (int i = 0; i < 4; ++i)
#pragma unroll
      for (int j = 0; j < 4; ++j)
        acc[i][j] = __builtin_amdgcn_mfma_f32_16x16x32_bf16(a[i], b[j], acc[i][j], 0, 0, 0);
    __builtin_amdgcn_s_setprio(0);
    cur = (cur < 2) ? cur + 1 : 0;
  }

#pragma unroll
  for (int i = 0; i < 4; ++i) {
    const int mrow = m0 + wr * 64 + i * 16 + lk * 4;
#pragma unroll
    for (int j = 0; j < 4; ++j) {
      const int col = n0 + wc * 64 + j * 16 + l16;
      const float bval = bias[col];
#pragma unroll
      for (int r = 0; r < 4; ++r) {
        const size_t idx = (size_t)(mrow + r) * N + col;
        Cf[idx] = acc[i][j][r] + bval + res[idx];
      }
    }
  }
}

// ---------------- in-place LayerNorm over rows of 1024 f32 ----------------
__global__ __launch_bounds__(256) void ln_kernel(float* __restrict__ y,
                                                 const float* __restrict__ gamma,
                                                 const float* __restrict__ beta) {
  __shared__ float ssum[4], ssq[4];
  const int tid = threadIdx.x;
  float* yr = y + ((size_t)blockIdx.x << 10);
  float4 v = *((const float4*)yr + tid);
  float s = v.x + v.y + v.z + v.w;
  float q2 = v.x * v.x + v.y * v.y + v.z * v.z + v.w * v.w;
#pragma unroll
  for (int off = 1; off < 64; off <<= 1) {
    s += __shfl_xor(s, off);
    q2 += __shfl_xor(q2, off);
  }
  if ((tid & 63) == 0) { ssum[tid >> 6] = s; ssq[tid >> 6] = q2; }
  __syncthreads();
  s = ssum[0] + ssum[1] + ssum[2] + ssum[3];
  q2 = ssq[0] + ssq[1] + ssq[2] + ssq[3];
  const float mu = s * (1.0f / 1024.0f);
  const float rstd = rsqrtf(q2 * (1.0f / 1024.0f) - mu * mu + 1e-5f);
  float4 g = *((const float4*)gamma + tid);
  float4 be = *((const float4*)beta + tid);
  float4 o;
  o.x = (v.x - mu) * rstd * g.x + be.x;
  o.y = (v.y - mu) * rstd * g.y + be.y;
  o.z = (v.z - mu) * rstd * g.z + be.z;
  o.w = (v.w - mu) * rstd * g.w + be.w;
  *((float4*)yr + tid) = o;
}

extern "C" void kernel_launch(void* const* d_in, const int* in_sizes, int n_in,
                              void* d_out, int out_size, void* d_ws, size_t ws_size,
                              hipStream_t stream) {
  (void)in_sizes; (void)n_in; (void)out_size; (void)ws_size;
  const float* q = (const float*)d_in[0];
  const float* k = (const float*)d_in[1];
  const float* v = (const float*)d_in[2];
  const int* msk = (const int*)d_in[3];
  const float* Wq = (const float*)d_in[4];
  const float* bq = (const float*)d_in[5];
  const float* Wk = (const float*)d_in[6];
  const float* bk = (const float*)d_in[7];
  const float* Wv = (const float*)d_in[8];
  const float* bv = (const float*)d_in[9];
  const float* Wo = (const float*)d_in[10];
  const float* bo = (const float*)d_in[11];
  const float* gamma = (const float*)d_in[12];
  const float* beta = (const float*)d_in[13];
  float* out = (float*)d_out;

  char* p = (char*)d_ws;
  auto take = [&p](size_t bytes) {
    char* r = p;
    p += (bytes + 255) & ~(size_t)255;
    return r;
  };
  u16* qb = (u16*)take(8192ull * 1024 * 2);
  u16* kb = (u16*)take(8192ull * 768 * 2);
  u16* vb = (u16*)take(8192ull * 768 * 2);
  u16* wqb = (u16*)take(1024ull * 1024 * 2);
  u16* wkb = (u16*)take(1024ull * 768 * 2);
  u16* wvb = (u16*)take(1024ull * 768 * 2);
  u16* wob = (u16*)take(1024ull * 1024 * 2);
  u16* qpb = (u16*)take(8192ull * 1024 * 2);
  u16* kpb = (u16*)take(8192ull * 1024 * 2);
  u16* vtb = (u16*)take(8192ull * 1024 * 2);  // [B][H][64][1024]
  u16* atb = (u16*)take(8192ull * 1024 * 2);

  cast_all<<<dim3(24064), 256, 0, stream>>>(q, k, v, Wq, Wk, Wv, Wo, qb);

  proj_kernel<<<dim3(32, 24), 256, 0, stream>>>(qb, kb, vb, wqb, wkb, wvb,
                                                bq, bk, bv, qpb, kpb, vtb);

  attn_kernel<<<dim3(2048), 256, 0, stream>>>(qpb, kpb, vtb, msk, atb);

  gemm_o<<<dim3(64, 8), 256, 0, stream>>>(atb, wob, bo, out, q);

  ln_kernel<<<dim3(8192), 256, 0, stream>>>(out, gamma, beta);
}

// Round 14
// 169.400 us; speedup vs baseline: 1.8383x; 1.0246x over previous
//
#include <hip/hip_runtime.h>
#include <stdint.h>

typedef float f32x4 __attribute__((ext_vector_type(4)));
typedef __bf16 bf16x8 __attribute__((ext_vector_type(8)));
typedef unsigned short u16;

__device__ __forceinline__ void gload_lds16(const void* g, void* l) {
  __builtin_amdgcn_global_load_lds(
      (__attribute__((address_space(1))) void*)(uintptr_t)(g),
      (__attribute__((address_space(3))) void*)(uint32_t)(uintptr_t)(l),
      16, 0, 0);
}

__device__ __forceinline__ u16 f2bf(float x) {
  __bf16 h = (__bf16)x;
  return *(u16*)&h;
}

__device__ __forceinline__ void barrier_raw() {
  __builtin_amdgcn_sched_barrier(0);
  __builtin_amdgcn_s_barrier();
  __builtin_amdgcn_sched_barrier(0);
}

#define VMCNT(n) asm volatile("s_waitcnt vmcnt(" #n ")" ::: "memory")

// ---------------- fused cast f32 -> bf16 for all 7 arrays ----------------
__global__ __launch_bounds__(256) void cast_all(
    const float* __restrict__ q, const float* __restrict__ k,
    const float* __restrict__ v, const float* __restrict__ wq,
    const float* __restrict__ wk, const float* __restrict__ wv,
    const float* __restrict__ wo, u16* __restrict__ out) {
  const int g = blockIdx.x;
  const float* in;
  int s;
  if (g < 8192) { in = q; s = 0; }
  else if (g < 14336) { in = k; s = 8192; }
  else if (g < 20480) { in = v; s = 14336; }
  else if (g < 21504) { in = wq; s = 20480; }
  else if (g < 22272) { in = wk; s = 21504; }
  else if (g < 23040) { in = wv; s = 22272; }
  else { in = wo; s = 23040; }
  const int li = (g - s) * 256 + threadIdx.x;
  float4 x = *((const float4*)in + li);
  unsigned lo = (unsigned)f2bf(x.x) | ((unsigned)f2bf(x.y) << 16);
  unsigned hi = (unsigned)f2bf(x.z) | ((unsigned)f2bf(x.w) << 16);
  ((uint2*)out)[(size_t)g * 256 + threadIdx.x] = make_uint2(lo, hi);
}

// ---------------- merged Q/K/V projection GEMM ----------------
// BM=256 x BN=128, 4 waves (128x64/wave). SINGLE-barrier K-loop, 3 buffers:
//   [vmcnt(6) -> barrier -> stage(kt+2) -> reads(kt) -> MFMA(kt)]
// Measured floor of the 2-barrier-class structure (66us): reg-dbuf (R9: 88),
// two-barrier (R10: 66), fat waves @1/SIMD (R12: 192) all lose or tie.
// Role grouping y>>3 keeps A panels XCD-L2-resident (R8: y%3 = -30%).
__global__ __launch_bounds__(256, 2) void proj_kernel(
    const u16* __restrict__ qb, const u16* __restrict__ kb,
    const u16* __restrict__ vb, const u16* __restrict__ wqb,
    const u16* __restrict__ wkb, const u16* __restrict__ wvb,
    const float* __restrict__ bq, const float* __restrict__ bk,
    const float* __restrict__ bv, u16* __restrict__ qpb,
    u16* __restrict__ kpb, u16* __restrict__ vtb) {
  __shared__ __align__(16) u16 As[3][256 * 32];
  __shared__ __align__(16) u16 Bs[3][128 * 32];
  const int tid = threadIdx.x;
  const int role = blockIdx.y >> 3;
  const int m0 = blockIdx.x * 256, n0 = (blockIdx.y & 7) * 128;
  const int K = (role == 0) ? 1024 : 768;
  const u16* A = (role == 0) ? qb : ((role == 1) ? kb : vb);
  const u16* Bt = (role == 0) ? wqb : ((role == 1) ? wkb : wvb);
  const float* bias = (role == 0) ? bq : ((role == 1) ? bk : bv);
  const int lane = tid & 63, w = tid >> 6;
  const int wr = w >> 1, wc = w & 1;
  const int l16 = lane & 15, lk = lane >> 4;
  const int nk = K >> 5;
  const int srow = tid >> 2;
  const int sw = (tid & 3) ^ ((tid >> 3) & 3);

  const u16* Ap = A + (size_t)(m0 + srow) * K + sw * 8;
  const u16* Bp = Bt + (size_t)(n0 + srow) * K + sw * 8;

  f32x4 acc[8][4] = {};

  auto stage = [&](int t, int ko) {
#pragma unroll
    for (int l = 0; l < 4; ++l)
      gload_lds16(Ap + (size_t)l * 64 * K + ko, As[t] + tid * 8 + l * 2048);
#pragma unroll
    for (int l = 0; l < 2; ++l)
      gload_lds16(Bp + (size_t)l * 64 * K + ko, Bs[t] + tid * 8 + l * 2048);
  };

  // prologue: tiles 0,1 in flight (12 loads)
  stage(0, 0);
  stage(1, 32);

  const int e2 = (l16 >> 1) & 3;  // read-side swizzle
  int cur = 0;
  for (int kt = 0; kt < nk; ++kt) {
    if (kt + 1 < nk) { VMCNT(6); } else { VMCNT(0); }
    barrier_raw();  // buf[cur] fully staged; buf[stg] fully consumed
    if (kt + 2 < nk) {
      const int stg = (cur >= 1) ? cur - 1 : 2;  // (cur+2)%3, consumed @ kt-1
      stage(stg, (kt + 2) << 5);
    }
    bf16x8 a[8], b[4];
#pragma unroll
    for (int i = 0; i < 8; ++i)
      a[i] = *(const bf16x8*)(As[cur] + (wr * 128 + i * 16 + l16) * 32 + (lk ^ e2) * 8);
#pragma unroll
    for (int j = 0; j < 4; ++j)
      b[j] = *(const bf16x8*)(Bs[cur] + (wc * 64 + j * 16 + l16) * 32 + (lk ^ e2) * 8);
    __builtin_amdgcn_s_setprio(1);
#pragma unroll
    for (int i = 0; i < 8; ++i)
#pragma unroll
      for (int j = 0; j < 4; ++j)
        acc[i][j] = __builtin_amdgcn_mfma_f32_16x16x32_bf16(a[i], b[j], acc[i][j], 0, 0, 0);
    __builtin_amdgcn_s_setprio(0);
    cur = (cur < 2) ? cur + 1 : 0;
  }

#pragma unroll
  for (int i = 0; i < 8; ++i) {
    const int mrow = m0 + wr * 128 + i * 16 + lk * 4;
#pragma unroll
    for (int j = 0; j < 4; ++j) {
      const int col = n0 + wc * 64 + j * 16 + l16;
      const float bval = bias[col];
      if (role == 0) {
#pragma unroll
        for (int r = 0; r < 4; ++r)
          qpb[(size_t)(mrow + r) * 1024 + col] = f2bf(acc[i][j][r] + bval);
      } else if (role == 1) {
#pragma unroll
        for (int r = 0; r < 4; ++r)
          kpb[(size_t)(mrow + r) * 1024 + col] = f2bf(acc[i][j][r] + bval);
      } else {  // vt[b][h][d][l], rows r are 4 consecutive l
        const int bb = mrow >> 10, l = mrow & 1023;
        const int hh = col >> 6, dd = col & 63;
        u16 u0 = f2bf(acc[i][j][0] + bval);
        u16 u1 = f2bf(acc[i][j][1] + bval);
        u16 u2 = f2bf(acc[i][j][2] + bval);
        u16 u3 = f2bf(acc[i][j][3] + bval);
        uint2 pkt = make_uint2((unsigned)u0 | ((unsigned)u1 << 16),
                               (unsigned)u2 | ((unsigned)u3 << 16));
        *(uint2*)(vtb + ((size_t)((bb * 16 + hh) * 64 + dd) << 10) + l) = pkt;
      }
    }
  }
}

// ---------------- fused masked flash attention (128-row Q blocks) ----------
// grid = 1024 flat, block = 256 (4 waves x 32 q-rows, two 16-row halves).
// Each K/V row read and each 16KB K/V stage now feeds 2x the MFMAs of the
// 64-row version (staging DMA, barriers, K/V ds_reads per FLOP all halve;
// softmax work is FLOP-proportional and unchanged). LDS 48KB -> 3 blocks/CU.
// XCD decode: bh = (bid&7) + 8*(bid>>6), qt = (bid>>3)&7 -> all 8 qt-blocks
// of one (b,h) share an XCD (16 bh x 256KB = 4MB = L2).
__global__ __launch_bounds__(256) void attn_kernel(
    const u16* __restrict__ qp, const u16* __restrict__ kp,
    const u16* __restrict__ vt, const int* __restrict__ mask,
    u16* __restrict__ out) {
  __shared__ __align__(16) u16 KV[2][2][64 * 64];  // [buf][0=K,1=V], 32KB
  __shared__ __align__(16) u16 Ps[4][32 * 64];     // per-wave P, 16KB
  const int tid = threadIdx.x;
  const int bid = blockIdx.x;
  const int qt = (bid >> 3) & 7;
  const int bh = (bid & 7) + ((bid >> 6) << 3);
  const int b = bh >> 4, h = bh & 15;
  const int lane = tid & 63, w = tid >> 6;
  const int l16 = lane & 15, lk = lane >> 4;
  const int srow = tid >> 3, schunk = tid & 7;
  const int sw = schunk ^ (srow & 7);  // pre-swizzled source chunk

  // per-wave prefix-mask popcount -> len (no LDS, no cross-wave comm)
  int cnt = 0;
  {
    const int4* mp = (const int4*)(mask + (b << 10));
#pragma unroll
    for (int i = 0; i < 4; ++i) {
      const int4 mv = mp[lane * 4 + i];
      cnt += (mv.x ? 1 : 0) + (mv.y ? 1 : 0) + (mv.z ? 1 : 0) + (mv.w ? 1 : 0);
    }
#pragma unroll
    for (int off = 1; off < 64; off <<= 1) cnt += __shfl_xor(cnt, off);
  }
  const int ntile = (cnt + 63) >> 6;
  const int rem = cnt & 63;

  // stage Q (128 rows, 16KB) into the KV[1] region; K0/V0 into KV[0]
  u16* qbase = &KV[1][0][0];
#pragma unroll
  for (int p = 0; p < 4; ++p)
    gload_lds16(qp + (((size_t)(b * 1024 + qt * 128 + p * 32 + srow)) << 10) + h * 64 + sw * 8,
                qbase + tid * 8 + p * 2048);
#pragma unroll
  for (int p = 0; p < 2; ++p) {
    gload_lds16(kp + (((size_t)(b * 1024 + p * 32 + srow)) << 10) + h * 64 + sw * 8,
                KV[0][0] + tid * 8 + p * 2048);
    gload_lds16(vt + (((size_t)((b * 16 + h) * 64 + p * 32 + srow)) << 10) + sw * 8,
                KV[0][1] + tid * 8 + p * 2048);
  }
  __syncthreads();
  const int e7 = l16 & 7;
  const int rowA = w * 32 + l16;  // rowA&7 == l16&7 == e7 (w*32 is 8-aligned)
  bf16x8 aqA0 = *(const bf16x8*)(qbase + rowA * 64 + (lk ^ e7) * 8);
  bf16x8 aqA1 = *(const bf16x8*)(qbase + rowA * 64 + ((lk + 4) ^ e7) * 8);
  bf16x8 aqB0 = *(const bf16x8*)(qbase + (rowA + 16) * 64 + (lk ^ e7) * 8);
  bf16x8 aqB1 = *(const bf16x8*)(qbase + (rowA + 16) * 64 + ((lk + 4) ^ e7) * 8);
  __syncthreads();  // all waves done with Q region before buf1 prefetch

  const float SC2 = 0.18033688011112042f;  // 0.125 * log2(e)
  float lsA = 0.f, lsB = 0.f;              // row sums for q = l16 (+16)
  f32x4 oaccA[4] = {}, oaccB[4] = {};

  int cur = 0;
  for (int kt = 0; kt < ntile; ++kt) {
    // issue next-tile prefetch FIRST (stays in flight across compute)
    if (kt + 1 < ntile) {
#pragma unroll
      for (int p = 0; p < 2; ++p) {
        gload_lds16(kp + (((size_t)(b * 1024 + (kt + 1) * 64 + p * 32 + srow)) << 10) + h * 64 + sw * 8,
                    KV[cur ^ 1][0] + tid * 8 + p * 2048);
        gload_lds16(vt + (((size_t)((b * 16 + h) * 64 + p * 32 + srow)) << 10) + (kt + 1) * 64 + sw * 8,
                    KV[cur ^ 1][1] + tid * 8 + p * 2048);
      }
    }
    const u16* Kb = KV[cur][0];
    const u16* Vb = KV[cur][1];

    // QK^T, swapped operands: lane holds S[key=nf*16+lk*4+r][q=l16] per half;
    // each K-row read feeds both halves (2 MFMA/ds_read).
    f32x4 sfA[4] = {}, sfB[4] = {};
    __builtin_amdgcn_s_setprio(1);
#pragma unroll
    for (int nf = 0; nf < 4; ++nf) {
      const int krow = nf * 16 + l16;
      bf16x8 bk0 = *(const bf16x8*)(Kb + krow * 64 + (lk ^ e7) * 8);
      bf16x8 bk1 = *(const bf16x8*)(Kb + krow * 64 + ((lk + 4) ^ e7) * 8);
      sfA[nf] = __builtin_amdgcn_mfma_f32_16x16x32_bf16(bk0, aqA0, sfA[nf], 0, 0, 0);
      sfA[nf] = __builtin_amdgcn_mfma_f32_16x16x32_bf16(bk1, aqA1, sfA[nf], 0, 0, 0);
      sfB[nf] = __builtin_amdgcn_mfma_f32_16x16x32_bf16(bk0, aqB0, sfB[nf], 0, 0, 0);
      sfB[nf] = __builtin_amdgcn_mfma_f32_16x16x32_bf16(bk1, aqB1, sfB[nf], 0, 0, 0);
    }
    __builtin_amdgcn_s_setprio(0);

    // fixed-shift softmax; only the single partial tile needs mask math
    const bool partial = (kt == ntile - 1) && (rem != 0);
    u16* Pw = &Ps[w][0];
#pragma unroll
    for (int nf = 0; nf < 4; ++nf) {
      float a0 = __builtin_amdgcn_exp2f(sfA[nf][0] * SC2);
      float a1 = __builtin_amdgcn_exp2f(sfA[nf][1] * SC2);
      float a2 = __builtin_amdgcn_exp2f(sfA[nf][2] * SC2);
      float a3 = __builtin_amdgcn_exp2f(sfA[nf][3] * SC2);
      float b0 = __builtin_amdgcn_exp2f(sfB[nf][0] * SC2);
      float b1 = __builtin_amdgcn_exp2f(sfB[nf][1] * SC2);
      float b2 = __builtin_amdgcn_exp2f(sfB[nf][2] * SC2);
      float b3 = __builtin_amdgcn_exp2f(sfB[nf][3] * SC2);
      if (partial) {
        const int k0 = nf * 16 + lk * 4;
        a0 = (k0 + 0 < rem) ? a0 : 0.f;  b0 = (k0 + 0 < rem) ? b0 : 0.f;
        a1 = (k0 + 1 < rem) ? a1 : 0.f;  b1 = (k0 + 1 < rem) ? b1 : 0.f;
        a2 = (k0 + 2 < rem) ? a2 : 0.f;  b2 = (k0 + 2 < rem) ? b2 : 0.f;
        a3 = (k0 + 3 < rem) ? a3 : 0.f;  b3 = (k0 + 3 < rem) ? b3 : 0.f;
      }
      lsA += (a0 + a1) + (a2 + a3);
      lsB += (b0 + b1) + (b2 + b3);
      const int chnk = ((nf * 2 + (lk >> 1)) ^ e7) * 8 + (lk & 1) * 4;
      *(uint2*)(Pw + l16 * 64 + chnk) = make_uint2(
          (unsigned)f2bf(a0) | ((unsigned)f2bf(a1) << 16),
          (unsigned)f2bf(a2) | ((unsigned)f2bf(a3) << 16));
      *(uint2*)(Pw + (16 + l16) * 64 + chnk) = make_uint2(
          (unsigned)f2bf(b0) | ((unsigned)f2bf(b1) << 16),
          (unsigned)f2bf(b2) | ((unsigned)f2bf(b3) << 16));
    }

    bf16x8 apA0 = *(const bf16x8*)(Pw + l16 * 64 + ((lk ^ e7) * 8));
    bf16x8 apA1 = *(const bf16x8*)(Pw + l16 * 64 + (((4 + lk) ^ e7) * 8));
    bf16x8 apB0 = *(const bf16x8*)(Pw + (16 + l16) * 64 + ((lk ^ e7) * 8));
    bf16x8 apB1 = *(const bf16x8*)(Pw + (16 + l16) * 64 + (((4 + lk) ^ e7) * 8));
    __builtin_amdgcn_s_setprio(1);
#pragma unroll
    for (int nf = 0; nf < 4; ++nf) {
      const int vrow = nf * 16 + l16;
      bf16x8 bv0 = *(const bf16x8*)(Vb + vrow * 64 + (lk ^ e7) * 8);
      bf16x8 bv1 = *(const bf16x8*)(Vb + vrow * 64 + ((lk + 4) ^ e7) * 8);
      oaccA[nf] = __builtin_amdgcn_mfma_f32_16x16x32_bf16(apA0, bv0, oaccA[nf], 0, 0, 0);
      oaccA[nf] = __builtin_amdgcn_mfma_f32_16x16x32_bf16(apA1, bv1, oaccA[nf], 0, 0, 0);
      oaccB[nf] = __builtin_amdgcn_mfma_f32_16x16x32_bf16(apB0, bv0, oaccB[nf], 0, 0, 0);
      oaccB[nf] = __builtin_amdgcn_mfma_f32_16x16x32_bf16(apB1, bv1, oaccB[nf], 0, 0, 0);
    }
    __builtin_amdgcn_s_setprio(0);

    __syncthreads();  // drains prefetch (vmcnt0) + all waves done with KV[cur]
    cur ^= 1;
  }

  // reduce row-sums across the 4 lanes sharing l16, redistribute to out layout
  lsA += __shfl_xor(lsA, 16);
  lsA += __shfl_xor(lsA, 32);
  lsB += __shfl_xor(lsB, 16);
  lsB += __shfl_xor(lsB, 32);
  float rinvA[4], rinvB[4];
#pragma unroll
  for (int r = 0; r < 4; ++r) {
    rinvA[r] = 1.0f / __shfl(lsA, lk * 4 + r);
    rinvB[r] = 1.0f / __shfl(lsB, lk * 4 + r);
  }

#pragma unroll
  for (int nf = 0; nf < 4; ++nf)
#pragma unroll
    for (int r = 0; r < 4; ++r) {
      const int tokA = b * 1024 + qt * 128 + w * 32 + lk * 4 + r;
      const int col = h * 64 + nf * 16 + l16;
      out[((size_t)tokA << 10) + col] = f2bf(oaccA[nf][r] * rinvA[r]);
      out[((size_t)(tokA + 16) << 10) + col] = f2bf(oaccB[nf][r] * rinvB[r]);
    }
}

// ---------------- O-projection GEMM + bias + f32 residual ----------------
// Single-barrier 3-buffer K-loop (vmcnt slack = 4); 48KB LDS -> 3 blocks/CU.
__global__ __launch_bounds__(256, 3) void gemm_o(
    const u16* __restrict__ A, const u16* __restrict__ Bt,
    const float* __restrict__ bias, float* __restrict__ Cf,
    const float* __restrict__ res) {
  __shared__ __align__(16) u16 As[3][128 * 32];
  __shared__ __align__(16) u16 Bs[3][128 * 32];
  const int K = 1024, N = 1024, nk = 32;
  const int tid = threadIdx.x;
  const int m0 = blockIdx.x * 128, n0 = blockIdx.y * 128;
  const int lane = tid & 63, w = tid >> 6;
  const int wr = w >> 1, wc = w & 1;
  const int l16 = lane & 15, lk = lane >> 4;
  const int srow = tid >> 2;
  const int sw = (tid & 3) ^ ((tid >> 3) & 3);
  const int e2 = (l16 >> 1) & 3;

  const u16* Ap = A + (size_t)(m0 + srow) * K + sw * 8;
  const u16* Bp = Bt + (size_t)(n0 + srow) * K + sw * 8;

  f32x4 acc[4][4] = {};

  auto stage = [&](int t, int ko) {
#pragma unroll
    for (int p = 0; p < 2; ++p) {
      gload_lds16(Ap + (size_t)p * 64 * K + ko, As[t] + tid * 8 + p * 2048);
      gload_lds16(Bp + (size_t)p * 64 * K + ko, Bs[t] + tid * 8 + p * 2048);
    }
  };

  stage(0, 0);
  stage(1, 32);

  int cur = 0;
  for (int kt = 0; kt < nk; ++kt) {
    if (kt + 1 < nk) { VMCNT(4); } else { VMCNT(0); }
    barrier_raw();
    if (kt + 2 < nk) {
      const int stg = (cur >= 1) ? cur - 1 : 2;
      stage(stg, (kt + 2) << 5);
    }
    bf16x8 a[4], b[4];
#pragma unroll
    for (int i = 0; i < 4; ++i)
      a[i] = *(const bf16x8*)(As[cur] + (wr * 64 + i * 16 + l16) * 32 + (lk ^ e2) * 8);
#pragma unroll
    for (int j = 0; j < 4; ++j)
      b[j] = *(const bf16x8*)(Bs[cur] + (wc * 64 + j * 16 + l16) * 32 + (lk ^ e2) * 8);
    __builtin_amdgcn_s_setprio(1);
#pragma unroll
    for (int i = 0; i < 4; ++i)
#pragma unroll
      for (int j = 0; j < 4; ++j)
        acc[i][j] = __builtin_amdgcn_mfma_f32_16x16x32_bf16(a[i], b[j], acc[i][j], 0, 0, 0);
    __builtin_amdgcn_s_setprio(0);
    cur = (cur < 2) ? cur + 1 : 0;
  }

#pragma unroll
  for (int i = 0; i < 4; ++i) {
    const int mrow = m0 + wr * 64 + i * 16 + lk * 4;
#pragma unroll
    for (int j = 0; j < 4; ++j) {
      const int col = n0 + wc * 64 + j * 16 + l16;
      const float bval = bias[col];
#pragma unroll
      for (int r = 0; r < 4; ++r) {
        const size_t idx = (size_t)(mrow + r) * N + col;
        Cf[idx] = acc[i][j][r] + bval + res[idx];
      }
    }
  }
}

// ---------------- in-place LayerNorm over rows of 1024 f32 ----------------
__global__ __launch_bounds__(256) void ln_kernel(float* __restrict__ y,
                                                 const float* __restrict__ gamma,
                                                 const float* __restrict__ beta) {
  __shared__ float ssum[4], ssq[4];
  const int tid = threadIdx.x;
  float* yr = y + ((size_t)blockIdx.x << 10);
  float4 v = *((const float4*)yr + tid);
  float s = v.x + v.y + v.z + v.w;
  float q2 = v.x * v.x + v.y * v.y + v.z * v.z + v.w * v.w;
#pragma unroll
  for (int off = 1; off < 64; off <<= 1) {
    s += __shfl_xor(s, off);
    q2 += __shfl_xor(q2, off);
  }
  if ((tid & 63) == 0) { ssum[tid >> 6] = s; ssq[tid >> 6] = q2; }
  __syncthreads();
  s = ssum[0] + ssum[1] + ssum[2] + ssum[3];
  q2 = ssq[0] + ssq[1] + ssq[2] + ssq[3];
  const float mu = s * (1.0f / 1024.0f);
  const float rstd = rsqrtf(q2 * (1.0f / 1024.0f) - mu * mu + 1e-5f);
  float4 g = *((const float4*)gamma + tid);
  float4 be = *((const float4*)beta + tid);
  float4 o;
  o.x = (v.x - mu) * rstd * g.x + be.x;
  o.y = (v.y - mu) * rstd * g.y + be.y;
  o.z = (v.z - mu) * rstd * g.z + be.z;
  o.w = (v.w - mu) * rstd * g.w + be.w;
  *((float4*)yr + tid) = o;
}

extern "C" void kernel_launch(void* const* d_in, const int* in_sizes, int n_in,
                              void* d_out, int out_size, void* d_ws, size_t ws_size,
                              hipStream_t stream) {
  (void)in_sizes; (void)n_in; (void)out_size; (void)ws_size;
  const float* q = (const float*)d_in[0];
  const float* k = (const float*)d_in[1];
  const float* v = (const float*)d_in[2];
  const int* msk = (const int*)d_in[3];
  const float* Wq = (const float*)d_in[4];
  const float* bq = (const float*)d_in[5];
  const float* Wk = (const float*)d_in[6];
  const float* bk = (const float*)d_in[7];
  const float* Wv = (const float*)d_in[8];
  const float* bv = (const float*)d_in[9];
  const float* Wo = (const float*)d_in[10];
  const float* bo = (const float*)d_in[11];
  const float* gamma = (const float*)d_in[12];
  const float* beta = (const float*)d_in[13];
  float* out = (float*)d_out;

  char* p = (char*)d_ws;
  auto take = [&p](size_t bytes) {
    char* r = p;
    p += (bytes + 255) & ~(size_t)255;
    return r;
  };
  u16* qb = (u16*)take(8192ull * 1024 * 2);
  u16* kb = (u16*)take(8192ull * 768 * 2);
  u16* vb = (u16*)take(8192ull * 768 * 2);
  u16* wqb = (u16*)take(1024ull * 1024 * 2);
  u16* wkb = (u16*)take(1024ull * 768 * 2);
  u16* wvb = (u16*)take(1024ull * 768 * 2);
  u16* wob = (u16*)take(1024ull * 1024 * 2);
  u16* qpb = (u16*)take(8192ull * 1024 * 2);
  u16* kpb = (u16*)take(8192ull * 1024 * 2);
  u16* vtb = (u16*)take(8192ull * 1024 * 2);  // [B][H][64][1024]
  u16* atb = (u16*)take(8192ull * 1024 * 2);

  cast_all<<<dim3(24064), 256, 0, stream>>>(q, k, v, Wq, Wk, Wv, Wo, qb);

  proj_kernel<<<dim3(32, 24), 256, 0, stream>>>(qb, kb, vb, wqb, wkb, wvb,
                                                bq, bk, bv, qpb, kpb, vtb);

  attn_kernel<<<dim3(1024), 256, 0, stream>>>(qpb, kpb, vtb, msk, atb);

  gemm_o<<<dim3(64, 8), 256, 0, stream>>>(atb, wob, bo, out, q);

  ln_kernel<<<dim3(8192), 256, 0, stream>>>(out, gamma, beta);
}